// Round 1
// baseline (129.564 us; speedup 1.0000x reference)
//
#include <hip/hip_runtime.h>

// entmax_bisect, alpha = 1.5, rows of N=2048 fp32, 50 bisection iterations.
// One wave64 per row; row data lives entirely in 32 VGPRs per lane.
// alpha-1 = 0.5, 1/(alpha-1) = 2.0  =>  power(d, 2) == d*d.
// hi = max(am1*z) == 0 exactly, lo = -1 (reference's expand loop is a no-op).

constexpr int N = 2048;
constexpr int PER_LANE = N / 64;      // 32 elements per lane
constexpr int WAVES_PER_BLOCK = 4;    // 256-thread blocks, 1 row per wave
constexpr int N_ITER = 50;

__global__ __launch_bounds__(256, 4)
void entmax15_bisect_kernel(const float* __restrict__ x,
                            float* __restrict__ out, int rows) {
    const int wave = threadIdx.x >> 6;
    const int lane = threadIdx.x & 63;
    const int row  = blockIdx.x * WAVES_PER_BLOCK + wave;
    if (row >= rows) return;

    const float4* xr  = reinterpret_cast<const float4*>(x   + (size_t)row * N);
    float4*       outr = reinterpret_cast<float4*>(out + (size_t)row * N);

    // Coalesced load: lane i takes float4 chunks i, i+64, ..., i+448.
    float v[PER_LANE];
    #pragma unroll
    for (int c = 0; c < PER_LANE / 4; ++c) {
        float4 t = xr[lane + 64 * c];
        v[4*c+0] = t.x; v[4*c+1] = t.y; v[4*c+2] = t.z; v[4*c+3] = t.w;
    }

    // Row max (exact: same element set as reference's jnp.max).
    float m = v[0];
    #pragma unroll
    for (int i = 1; i < PER_LANE; ++i) m = fmaxf(m, v[i]);
    #pragma unroll
    for (int off = 32; off >= 1; off >>= 1)
        m = fmaxf(m, __shfl_xor(m, off, 64));

    // v = (alpha-1)*(x - max) = 0.5*x - 0.5*m  (exact wrt 0.5*(x-m): *0.5 is exact)
    const float nhm = -0.5f * m;
    #pragma unroll
    for (int i = 0; i < PER_LANE; ++i) v[i] = fmaf(0.5f, v[i], nhm);

    float lo = -1.0f, hi = 0.0f;
    for (int it = 0; it < N_ITER; ++it) {
        const float mid = 0.5f * (lo + hi);
        // 4 independent accumulators: shorten the fma dependency chain.
        float s0 = 0.f, s1 = 0.f, s2 = 0.f, s3 = 0.f;
        #pragma unroll
        for (int i = 0; i < PER_LANE; i += 4) {
            float d0 = fmaxf(v[i+0] - mid, 0.f);
            float d1 = fmaxf(v[i+1] - mid, 0.f);
            float d2 = fmaxf(v[i+2] - mid, 0.f);
            float d3 = fmaxf(v[i+3] - mid, 0.f);
            s0 = fmaf(d0, d0, s0);
            s1 = fmaf(d1, d1, s1);
            s2 = fmaf(d2, d2, s2);
            s3 = fmaf(d3, d3, s3);
        }
        float s = (s0 + s1) + (s2 + s3);
        #pragma unroll
        for (int off = 32; off >= 1; off >>= 1)
            s += __shfl_xor(s, off, 64);
        // Wave-uniform after butterfly reduce: no divergence.
        if (s > 1.0f) lo = mid; else hi = mid;
    }
    const float tau = 0.5f * (lo + hi);

    // p = max(v - tau, 0)^2 ; normalize by max(sum(p), 1e-12).
    float s0 = 0.f, s1 = 0.f, s2 = 0.f, s3 = 0.f;
    #pragma unroll
    for (int i = 0; i < PER_LANE; i += 4) {
        float d0 = fmaxf(v[i+0] - tau, 0.f);
        float d1 = fmaxf(v[i+1] - tau, 0.f);
        float d2 = fmaxf(v[i+2] - tau, 0.f);
        float d3 = fmaxf(v[i+3] - tau, 0.f);
        v[i+0] = d0 * d0; v[i+1] = d1 * d1;
        v[i+2] = d2 * d2; v[i+3] = d3 * d3;
        s0 += v[i+0]; s1 += v[i+1]; s2 += v[i+2]; s3 += v[i+3];
    }
    float s = (s0 + s1) + (s2 + s3);
    #pragma unroll
    for (int off = 32; off >= 1; off >>= 1)
        s += __shfl_xor(s, off, 64);
    const float inv = 1.0f / fmaxf(s, 1e-12f);

    #pragma unroll
    for (int c = 0; c < PER_LANE / 4; ++c) {
        float4 t;
        t.x = v[4*c+0] * inv;
        t.y = v[4*c+1] * inv;
        t.z = v[4*c+2] * inv;
        t.w = v[4*c+3] * inv;
        outr[lane + 64 * c] = t;
    }
}

extern "C" void kernel_launch(void* const* d_in, const int* in_sizes, int n_in,
                              void* d_out, int out_size, void* d_ws, size_t ws_size,
                              hipStream_t stream) {
    const float* x = (const float*)d_in[0];
    float* out = (float*)d_out;
    const int rows = in_sizes[0] / N;                       // 8*2048 = 16384
    const int blocks = (rows + WAVES_PER_BLOCK - 1) / WAVES_PER_BLOCK;
    entmax15_bisect_kernel<<<blocks, 64 * WAVES_PER_BLOCK, 0, stream>>>(x, out, rows);
}

// Round 2
// 66.600 us; speedup vs baseline: 1.9454x; 1.9454x over previous
//
#include <hip/hip_runtime.h>

// entmax_bisect, alpha = 1.5, rows of N=2048 fp32, 50 bisection iterations.
// One wave64 per row; row lives in 32 VGPRs/lane.
// alpha-1 = 0.5, 1/(alpha-1) = 2  =>  power(d, 1/am1) == d*d.
// hi = max(am1*z) == 0 exactly, lo = -1 (reference expand loop is a no-op).
//
// Three-phase bisection:
//   P1: K1=10 full-pass iterations -> bracket width 2^-10.
//   P2: one pass: aggregates (n, S1, S2) over certain-support {v > hi_f}
//       (centered at c=hi_f to avoid cancellation) + LDS-compact the <=4
//       boundary elements in (lo_f, hi_f].
//   P3: K2=40 iterations at O(1): s(mid) = n*t^2 - 2*S1*t + S2 (t=mid-c)
//       + 4 boundary terms. Exact partition of the reference sum.
//   Fallback: if >4 boundary elements (never for iid normal data), the wave
//   runs full passes for the remaining 40 iterations.

constexpr int N = 2048;
constexpr int PER_LANE = N / 64;      // 32
constexpr int WAVES_PER_BLOCK = 4;    // 256-thread blocks
constexpr int K1 = 10;
constexpr int K2 = 40;
constexpr int BMAX = 4;

__global__ __launch_bounds__(256, 4)
void entmax15_bisect_kernel(const float* __restrict__ x,
                            float* __restrict__ out, int rows) {
    __shared__ float s_buf[WAVES_PER_BLOCK][BMAX];
    __shared__ int   s_cnt[WAVES_PER_BLOCK];

    const int wave = threadIdx.x >> 6;
    const int lane = threadIdx.x & 63;
    const int row  = blockIdx.x * WAVES_PER_BLOCK + wave;
    if (row >= rows) return;   // rows % WAVES_PER_BLOCK == 0: never divergent

    const float4* xr   = reinterpret_cast<const float4*>(x   + (size_t)row * N);
    float4*       outr = reinterpret_cast<float4*>(out + (size_t)row * N);

    float v[PER_LANE];
    #pragma unroll
    for (int c = 0; c < PER_LANE / 4; ++c) {
        float4 t = xr[lane + 64 * c];
        v[4*c+0] = t.x; v[4*c+1] = t.y; v[4*c+2] = t.z; v[4*c+3] = t.w;
    }

    // Row max.
    float m = v[0];
    #pragma unroll
    for (int i = 1; i < PER_LANE; ++i) m = fmaxf(m, v[i]);
    #pragma unroll
    for (int off = 32; off >= 1; off >>= 1)
        m = fmaxf(m, __shfl_xor(m, off, 64));

    // v = 0.5*x - 0.5*m
    const float nhm = -0.5f * m;
    #pragma unroll
    for (int i = 0; i < PER_LANE; ++i) v[i] = fmaf(0.5f, v[i], nhm);

    float lo = -1.0f, hi = 0.0f;

    // ---- Phase 1: full-pass bisection ----
    for (int it = 0; it < K1; ++it) {
        const float mid = 0.5f * (lo + hi);
        float s0 = 0.f, s1_ = 0.f, s2_ = 0.f, s3_ = 0.f;
        #pragma unroll
        for (int i = 0; i < PER_LANE; i += 4) {
            float d0 = fmaxf(v[i+0] - mid, 0.f);
            float d1 = fmaxf(v[i+1] - mid, 0.f);
            float d2 = fmaxf(v[i+2] - mid, 0.f);
            float d3 = fmaxf(v[i+3] - mid, 0.f);
            s0 = fmaf(d0, d0, s0); s1_ = fmaf(d1, d1, s1_);
            s2_ = fmaf(d2, d2, s2_); s3_ = fmaf(d3, d3, s3_);
        }
        float s = (s0 + s1_) + (s2_ + s3_);
        #pragma unroll
        for (int off = 32; off >= 1; off >>= 1)
            s += __shfl_xor(s, off, 64);
        if (s > 1.0f) lo = mid; else hi = mid;
    }

    // ---- Phase 2: aggregates + boundary compaction ----
    if (lane < BMAX) s_buf[wave][lane] = -1e30f;
    if (lane == 0)   s_cnt[wave] = 0;
    __syncthreads();

    const float cth = hi, lof = lo;     // frozen bracket
    float nA = 0.f, S1 = 0.f, S2 = 0.f;
    #pragma unroll
    for (int i = 0; i < PER_LANE; ++i) {
        float u  = v[i] - cth;
        float um = fmaxf(u, 0.f);
        nA += (u > 0.f) ? 1.0f : 0.0f;
        S1 += um;
        S2 = fmaf(um, um, S2);
        if (u <= 0.f && v[i] > lof) {          // boundary: rare
            int k = atomicAdd(&s_cnt[wave], 1);
            if (k < BMAX) s_buf[wave][k] = v[i];
        }
    }
    #pragma unroll
    for (int off = 32; off >= 1; off >>= 1) {
        nA += __shfl_xor(nA, off, 64);
        S1 += __shfl_xor(S1, off, 64);
        S2 += __shfl_xor(S2, off, 64);
    }
    __syncthreads();

    const int cnt = s_cnt[wave];        // wave-uniform
    float b0 = s_buf[wave][0], b1 = s_buf[wave][1];
    float b2 = s_buf[wave][2], b3 = s_buf[wave][3];
    // Sort descending (determinism independent of atomic append order).
    {
        float t;
        t = fmaxf(b0,b1); b1 = fminf(b0,b1); b0 = t;
        t = fmaxf(b2,b3); b3 = fminf(b2,b3); b2 = t;
        t = fmaxf(b0,b2); b2 = fminf(b0,b2); b0 = t;
        t = fmaxf(b1,b3); b3 = fminf(b1,b3); b1 = t;
        t = fmaxf(b1,b2); b2 = fminf(b1,b2); b1 = t;
    }

    // ---- Phase 3 ----
    if (cnt <= BMAX) {
        const float c1 = -2.0f * S1;
        for (int it = 0; it < K2; ++it) {
            const float mid = 0.5f * (lo + hi);
            const float t   = mid - cth;
            float s = fmaf(t, fmaf(nA, t, c1), S2);
            float d0 = fmaxf(b0 - mid, 0.f); s = fmaf(d0, d0, s);
            float d1 = fmaxf(b1 - mid, 0.f); s = fmaf(d1, d1, s);
            float d2 = fmaxf(b2 - mid, 0.f); s = fmaf(d2, d2, s);
            float d3 = fmaxf(b3 - mid, 0.f); s = fmaf(d3, d3, s);
            if (s > 1.0f) lo = mid; else hi = mid;
        }
    } else {
        // Fallback: full passes (correctness for adversarial inputs).
        for (int it = 0; it < K2; ++it) {
            const float mid = 0.5f * (lo + hi);
            float s0 = 0.f, s1_ = 0.f, s2_ = 0.f, s3_ = 0.f;
            #pragma unroll
            for (int i = 0; i < PER_LANE; i += 4) {
                float d0 = fmaxf(v[i+0] - mid, 0.f);
                float d1 = fmaxf(v[i+1] - mid, 0.f);
                float d2 = fmaxf(v[i+2] - mid, 0.f);
                float d3 = fmaxf(v[i+3] - mid, 0.f);
                s0 = fmaf(d0, d0, s0); s1_ = fmaf(d1, d1, s1_);
                s2_ = fmaf(d2, d2, s2_); s3_ = fmaf(d3, d3, s3_);
            }
            float s = (s0 + s1_) + (s2_ + s3_);
            #pragma unroll
            for (int off = 32; off >= 1; off >>= 1)
                s += __shfl_xor(s, off, 64);
            if (s > 1.0f) lo = mid; else hi = mid;
        }
    }
    const float tau = 0.5f * (lo + hi);

    // ---- Epilogue: p = max(v - tau, 0)^2, normalize ----
    float s0 = 0.f, s1_ = 0.f, s2_ = 0.f, s3_ = 0.f;
    #pragma unroll
    for (int i = 0; i < PER_LANE; i += 4) {
        float d0 = fmaxf(v[i+0] - tau, 0.f);
        float d1 = fmaxf(v[i+1] - tau, 0.f);
        float d2 = fmaxf(v[i+2] - tau, 0.f);
        float d3 = fmaxf(v[i+3] - tau, 0.f);
        v[i+0] = d0 * d0; v[i+1] = d1 * d1;
        v[i+2] = d2 * d2; v[i+3] = d3 * d3;
        s0 += v[i+0]; s1_ += v[i+1]; s2_ += v[i+2]; s3_ += v[i+3];
    }
    float s = (s0 + s1_) + (s2_ + s3_);
    #pragma unroll
    for (int off = 32; off >= 1; off >>= 1)
        s += __shfl_xor(s, off, 64);
    const float inv = 1.0f / fmaxf(s, 1e-12f);

    #pragma unroll
    for (int c = 0; c < PER_LANE / 4; ++c) {
        float4 t;
        t.x = v[4*c+0] * inv;
        t.y = v[4*c+1] * inv;
        t.z = v[4*c+2] * inv;
        t.w = v[4*c+3] * inv;
        outr[lane + 64 * c] = t;
    }
}

extern "C" void kernel_launch(void* const* d_in, const int* in_sizes, int n_in,
                              void* d_out, int out_size, void* d_ws, size_t ws_size,
                              hipStream_t stream) {
    const float* x = (const float*)d_in[0];
    float* out = (float*)d_out;
    const int rows = in_sizes[0] / N;                       // 16384
    const int blocks = (rows + WAVES_PER_BLOCK - 1) / WAVES_PER_BLOCK;
    entmax15_bisect_kernel<<<blocks, 64 * WAVES_PER_BLOCK, 0, stream>>>(x, out, rows);
}

// Round 3
// 57.324 us; speedup vs baseline: 2.2602x; 1.1618x over previous
//
#include <hip/hip_runtime.h>

// entmax_bisect, alpha=1.5, rows of N=2048 fp32. One wave64 per row, row in
// 32 VGPRs/lane. am1=0.5 => power(d,1/am1)=d*d; bracket starts (lo,hi)=(-1,0).
// v = 0.5*x - 0.5*max  =>  max element maps to exactly 0.
//
// P1: K1=6 full-pass bisection iters -> bracket width 2^-6, invariant
//     s(lo) > 1 >= s(hi).
// P2: one pass: aggregates (n, S1, S2) over certain support {v > hi}
//     (centered at c=hi), LDS-compact boundary elements in (lo, hi] (<=8).
// P3: sort boundary desc; greedy prefix-accept b_k iff s_agg(b_k) < 1
//     (s monotone => greedy finds the consistent support); closed-form root
//     tau = c + (S1 - sqrt(S1^2 - n(S2-1)))/n. Equals the reference's
//     50-iter bisection limit to within 2^-44 << fp32 rounding.
// Fallback (cnt > 8, ~never for iid data): 44 more full-pass iterations.

constexpr int N = 2048;
constexpr int PER_LANE = N / 64;      // 32
constexpr int WAVES_PER_BLOCK = 4;    // 256-thread blocks
constexpr int K1 = 6;
constexpr int TOTAL_ITER = 50;
constexpr int BMAX = 8;

__global__ __launch_bounds__(256, 4)
void entmax15_kernel(const float* __restrict__ x,
                     float* __restrict__ out, int rows) {
    __shared__ float s_buf[WAVES_PER_BLOCK][BMAX];
    __shared__ int   s_cnt[WAVES_PER_BLOCK];

    const int wave = threadIdx.x >> 6;
    const int lane = threadIdx.x & 63;
    const int row  = blockIdx.x * WAVES_PER_BLOCK + wave;
    if (row >= rows) return;           // rows % 4 == 0: never divergent

    const float4* xr   = reinterpret_cast<const float4*>(x   + (size_t)row * N);
    float4*       outr = reinterpret_cast<float4*>(out + (size_t)row * N);

    float v[PER_LANE];
    #pragma unroll
    for (int c = 0; c < PER_LANE / 4; ++c) {
        float4 t = xr[lane + 64 * c];
        v[4*c+0] = t.x; v[4*c+1] = t.y; v[4*c+2] = t.z; v[4*c+3] = t.w;
    }

    // Row max.
    float m = v[0];
    #pragma unroll
    for (int i = 1; i < PER_LANE; ++i) m = fmaxf(m, v[i]);
    #pragma unroll
    for (int off = 32; off >= 1; off >>= 1)
        m = fmaxf(m, __shfl_xor(m, off, 64));

    // v = 0.5*x - 0.5*m  (argmax element -> exactly 0)
    const float nhm = -0.5f * m;
    #pragma unroll
    for (int i = 0; i < PER_LANE; ++i) v[i] = fmaf(0.5f, v[i], nhm);

    float lo = -1.0f, hi = 0.0f;

    // ---- Phase 1: 6 full-pass bisection iterations ----
    for (int it = 0; it < K1; ++it) {
        const float mid = 0.5f * (lo + hi);
        float s0 = 0.f, s1_ = 0.f, s2_ = 0.f, s3_ = 0.f;
        #pragma unroll
        for (int i = 0; i < PER_LANE; i += 4) {
            float d0 = fmaxf(v[i+0] - mid, 0.f);
            float d1 = fmaxf(v[i+1] - mid, 0.f);
            float d2 = fmaxf(v[i+2] - mid, 0.f);
            float d3 = fmaxf(v[i+3] - mid, 0.f);
            s0 = fmaf(d0, d0, s0); s1_ = fmaf(d1, d1, s1_);
            s2_ = fmaf(d2, d2, s2_); s3_ = fmaf(d3, d3, s3_);
        }
        float s = (s0 + s1_) + (s2_ + s3_);
        #pragma unroll
        for (int off = 32; off >= 1; off >>= 1)
            s += __shfl_xor(s, off, 64);
        if (s > 1.0f) lo = mid; else hi = mid;
    }

    // ---- Phase 2: aggregates over certain support + boundary compaction ----
    if (lane < BMAX) s_buf[wave][lane] = -1e30f;
    if (lane == 0)   s_cnt[wave] = 0;
    // Per-wave private LDS; wave program order makes init visible to the
    // atomics below and those to the reads after the loop (same-wave DS ops
    // complete in order).

    const float cth = hi, lof = lo;
    float nA = 0.f, S1 = 0.f, S2 = 0.f;
    #pragma unroll
    for (int i = 0; i < PER_LANE; ++i) {
        float u  = v[i] - cth;
        float um = fmaxf(u, 0.f);
        nA += (u > 0.f) ? 1.0f : 0.0f;
        S1 += um;
        S2 = fmaf(um, um, S2);
        if (u <= 0.f && v[i] > lof) {              // boundary: rare
            int k = atomicAdd(&s_cnt[wave], 1);
            if (k < BMAX) s_buf[wave][k] = v[i];
        }
    }
    #pragma unroll
    for (int off = 32; off >= 1; off >>= 1) {
        nA += __shfl_xor(nA, off, 64);
        S1 += __shfl_xor(S1, off, 64);
        S2 += __shfl_xor(S2, off, 64);
    }

    const int cnt = s_cnt[wave];                   // wave-uniform
    float b0 = s_buf[wave][0], b1 = s_buf[wave][1];
    float b2 = s_buf[wave][2], b3 = s_buf[wave][3];
    float b4 = s_buf[wave][4], b5 = s_buf[wave][5];
    float b6 = s_buf[wave][6], b7 = s_buf[wave][7];

    float tau;
    bool fast = (cnt <= BMAX);
    if (fast) {
        // Sort b0..b7 descending (Batcher odd-even merge, 19 CEs).
        // Sentinels (-1e30) sink to the tail.
        #define CE(a, b) { float _t = fmaxf(a, b); b = fminf(a, b); a = _t; }
        CE(b0,b1) CE(b2,b3) CE(b4,b5) CE(b6,b7)
        CE(b0,b2) CE(b1,b3) CE(b4,b6) CE(b5,b7)
        CE(b1,b2) CE(b5,b6)
        CE(b0,b4) CE(b1,b5) CE(b2,b6) CE(b3,b7)
        CE(b2,b4) CE(b3,b5)
        CE(b1,b2) CE(b3,b4) CE(b5,b6)
        #undef CE

        // Greedy prefix-accept. For sentinels t ~ -1e30 => s = +inf => reject.
        float nk = nA, S1k = S1, S2k = S2;
        #define STEP(bk) {                                                  \
            float t_  = bk - cth;                                           \
            float sc_ = fmaf(t_, fmaf(nk, t_, -2.0f * S1k), S2k);           \
            bool  ac_ = sc_ < 1.0f;                                         \
            float ta_ = ac_ ? t_ : 0.0f;                                    \
            nk  += ac_ ? 1.0f : 0.0f;                                       \
            S1k += ta_;                                                     \
            S2k  = fmaf(ta_, ta_, S2k); }
        STEP(b0) STEP(b1) STEP(b2) STEP(b3)
        STEP(b4) STEP(b5) STEP(b6) STEP(b7)
        #undef STEP

        // Closed-form root of nk*t^2 - 2*S1k*t + (S2k - 1) = 0 (smaller root).
        float disc = fmaxf(fmaf(S1k, S1k, -nk * (S2k - 1.0f)), 0.0f);
        float t = (S1k - sqrtf(disc)) / nk;
        tau = cth + t;
    } else {
        // Fallback: finish all 44 remaining reference iterations.
        for (int it = 0; it < TOTAL_ITER - K1; ++it) {
            const float mid = 0.5f * (lo + hi);
            float s0 = 0.f, s1_ = 0.f, s2_ = 0.f, s3_ = 0.f;
            #pragma unroll
            for (int i = 0; i < PER_LANE; i += 4) {
                float d0 = fmaxf(v[i+0] - mid, 0.f);
                float d1 = fmaxf(v[i+1] - mid, 0.f);
                float d2 = fmaxf(v[i+2] - mid, 0.f);
                float d3 = fmaxf(v[i+3] - mid, 0.f);
                s0 = fmaf(d0, d0, s0); s1_ = fmaf(d1, d1, s1_);
                s2_ = fmaf(d2, d2, s2_); s3_ = fmaf(d3, d3, s3_);
            }
            float s = (s0 + s1_) + (s2_ + s3_);
            #pragma unroll
            for (int off = 32; off >= 1; off >>= 1)
                s += __shfl_xor(s, off, 64);
            if (s > 1.0f) lo = mid; else hi = mid;
        }
        tau = 0.5f * (lo + hi);
    }

    // ---- Epilogue: p = max(v - tau, 0)^2, normalize by elementwise sum ----
    float s0 = 0.f, s1_ = 0.f, s2_ = 0.f, s3_ = 0.f;
    #pragma unroll
    for (int i = 0; i < PER_LANE; i += 4) {
        float d0 = fmaxf(v[i+0] - tau, 0.f);
        float d1 = fmaxf(v[i+1] - tau, 0.f);
        float d2 = fmaxf(v[i+2] - tau, 0.f);
        float d3 = fmaxf(v[i+3] - tau, 0.f);
        v[i+0] = d0 * d0; v[i+1] = d1 * d1;
        v[i+2] = d2 * d2; v[i+3] = d3 * d3;
        s0 += v[i+0]; s1_ += v[i+1]; s2_ += v[i+2]; s3_ += v[i+3];
    }
    float s = (s0 + s1_) + (s2_ + s3_);
    #pragma unroll
    for (int off = 32; off >= 1; off >>= 1)
        s += __shfl_xor(s, off, 64);
    const float inv = 1.0f / fmaxf(s, 1e-12f);

    #pragma unroll
    for (int c = 0; c < PER_LANE / 4; ++c) {
        float4 t;
        t.x = v[4*c+0] * inv;
        t.y = v[4*c+1] * inv;
        t.z = v[4*c+2] * inv;
        t.w = v[4*c+3] * inv;
        outr[lane + 64 * c] = t;
    }
}

extern "C" void kernel_launch(void* const* d_in, const int* in_sizes, int n_in,
                              void* d_out, int out_size, void* d_ws, size_t ws_size,
                              hipStream_t stream) {
    const float* x = (const float*)d_in[0];
    float* out = (float*)d_out;
    const int rows = in_sizes[0] / N;                       // 16384
    const int blocks = (rows + WAVES_PER_BLOCK - 1) / WAVES_PER_BLOCK;
    entmax15_kernel<<<blocks, 64 * WAVES_PER_BLOCK, 0, stream>>>(x, out, rows);
}